// Round 3
// baseline (254.369 us; speedup 1.0000x reference)
//
#include <hip/hip_runtime.h>
#include <math.h>

#define BB 32
#define AA 5
#define CC 80
#define HH 52
#define WW 52
#define NBOX 50
#define HWSZ (HH*WW)          // 2704
#define CELLS (AA*HWSZ)       // 13520

__constant__ float d_aw[AA] = {1.3221f, 3.19275f, 5.05587f, 9.47112f, 11.2364f};
__constant__ float d_ah[AA] = {1.73145f, 4.00944f, 8.09892f, 4.84053f, 10.0071f};

__device__ __forceinline__ float sig(float x) { return 1.f / (1.f + expf(-x)); }

// d_ws layout:
//   lbox : float4[BB][NBOX][2]   (box-loop data)   offset 0
//     l0: ax1, ax2, ay1, ay2     (corner gt box; zeros if invalid)
//     l1: a375 = 0.375*area, cellf = a*2704+gj*52+gi (-1 if invalid), 0, 0
//   winfo: float4[BB][NBOX][2]   (winner data)     offset BB*NBOX*2
//     w0: tx_t, ty_t, tw_t, th_t
//     w1: iou_gt, cls, valid, is_last
#define LBOX_OFF  0
#define WINFO_OFF (BB * NBOX * 2)

__device__ __forceinline__ void cell_of(const float* t, int& best, int& gi, int& gj, float& valid) {
    float gx = t[1] * (float)WW;
    float gy = t[2] * (float)HH;
    float gw = t[3] * (float)WW;
    float gh = t[4] * (float)HH;
    valid = (t[1] > 0.f) ? 1.f : 0.f;
    best = 0; float bestv = -1.f;
    #pragma unroll
    for (int a = 0; a < AA; ++a) {
        float inter = fminf(gw, d_aw[a]) * fminf(gh, d_ah[a]);
        float uni = gw * gh + d_aw[a] * d_ah[a] - inter;
        float r = inter / uni;
        if (r > bestv) { bestv = r; best = a; }
    }
    gi = (int)gx; gi = gi < 0 ? 0 : (gi > WW - 1 ? WW - 1 : gi);
    gj = (int)gy; gj = gj < 0 ? 0 : (gj > HH - 1 ? HH - 1 : gj);
}

__global__ void region_prep(const float* __restrict__ pred,
                            const float* __restrict__ target,
                            float4* __restrict__ ws,
                            float* __restrict__ out, int out_size) {
    int b = blockIdx.x;
    int j = threadIdx.x;
    if (b == 0 && j >= NBOX) {          // zero the output scalar(s)
        for (int k = j - NBOX; k < out_size; k += 64 - NBOX) out[k] = 0.f;
    }
    if (j >= NBOX) return;
    const float* t = target + ((size_t)b * NBOX + j) * 5;
    float gx = t[1] * (float)WW;
    float gy = t[2] * (float)HH;
    float gw = t[3] * (float)WW;
    float gh = t[4] * (float)HH;
    int best, gi, gj; float valid;
    cell_of(t, best, gi, gj, valid);

    float tx_t = gx - (float)gi;
    float ty_t = gy - (float)gj;
    float tw_t = logf(gw / d_aw[best]);
    float th_t = logf(gh / d_ah[best]);

    // predicted box at (b, best, gj, gi)
    size_t base = ((size_t)(b * AA + best) * (CC + 5)) * HWSZ + (size_t)gj * WW + gi;
    float px = sig(pred[base]) + (float)gi;
    float py = sig(pred[base + HWSZ]) + (float)gj;
    float pw = expf(pred[base + 2 * HWSZ]) * d_aw[best];
    float ph = expf(pred[base + 3 * HWSZ]) * d_ah[best];

    float ax1 = gx - gw * 0.5f, ax2 = gx + gw * 0.5f;
    float ay1 = gy - gh * 0.5f, ay2 = gy + gh * 0.5f;
    float bx1 = px - pw * 0.5f, bx2 = px + pw * 0.5f;
    float by1 = py - ph * 0.5f, by2 = py + ph * 0.5f;
    float iw = fmaxf(fminf(ax2, bx2) - fmaxf(ax1, bx1), 0.f);
    float ih = fmaxf(fminf(ay2, by2) - fmaxf(ay1, by1), 0.f);
    float inter = iw * ih;
    float iou_gt = inter / (gw * gh + pw * ph - inter);

    // last-writer flag: any later valid box mapping to the same cell?
    float is_last = 1.f;
    for (int j2 = j + 1; j2 < NBOX; ++j2) {
        const float* t2 = target + ((size_t)b * NBOX + j2) * 5;
        int b2, i2, jj2; float v2;
        cell_of(t2, b2, i2, jj2, v2);
        if (v2 != 0.f && b2 == best && i2 == gi && jj2 == gj) is_last = 0.f;
    }

    float cellf = (float)(best * HWSZ + gj * WW + gi);
    float4* l = ws + LBOX_OFF + ((size_t)b * NBOX + j) * 2;
    if (valid != 0.f) {
        l[0] = make_float4(ax1, ax2, ay1, ay2);
        l[1] = make_float4(0.375f * gw * gh, cellf, 0.f, 0.f);
    } else {
        l[0] = make_float4(0.f, 0.f, 0.f, 0.f);
        l[1] = make_float4(0.f, -1.f, 0.f, 0.f);
    }
    float4* w = ws + WINFO_OFF + ((size_t)b * NBOX + j) * 2;
    w[0] = make_float4(tx_t, ty_t, tw_t, th_t);
    w[1] = make_float4(iou_gt, t[0], valid, is_last);
}

__device__ __forceinline__ float wave_max(float v) {
    #pragma unroll
    for (int off = 32; off > 0; off >>= 1) v = fmaxf(v, __shfl_xor(v, off, 64));
    return v;
}
__device__ __forceinline__ float wave_sum(float v) {
    #pragma unroll
    for (int off = 32; off > 0; off >>= 1) v += __shfl_xor(v, off, 64);
    return v;
}

// Class cross-entropy: one wave per (batch, winning box). 80 logits across lanes.
__global__ __launch_bounds__(256) void region_ce(const float* __restrict__ pred,
                                                 const float4* __restrict__ ws,
                                                 float* __restrict__ out) {
    int b = blockIdx.x;
    int wave = threadIdx.x >> 6;
    int lane = threadIdx.x & 63;
    float acc = 0.f;
    for (int j = wave; j < NBOX; j += 4) {
        const float4* w = ws + WINFO_OFF + ((size_t)b * NBOX + j) * 2;
        const float4* l = ws + LBOX_OFF + ((size_t)b * NBOX + j) * 2;
        float4 w1 = w[1];
        if (w1.z == 0.f || w1.w == 0.f) continue;   // not valid or not last writer
        int cell = (int)l[1].y;                      // a*2704 + gj*52 + gi
        int a = cell / HWSZ;
        int rem = cell - a * HWSZ;
        size_t cbase = ((size_t)(b * AA + a) * (CC + 5) + 5) * HWSZ + rem;
        float v1 = pred[cbase + (size_t)lane * HWSZ];
        float v2 = (lane < CC - 64) ? pred[cbase + (size_t)(lane + 64) * HWSZ] : -INFINITY;
        float mx = wave_max(fmaxf(v1, v2));
        float s = expf(v1 - mx) + ((lane < CC - 64) ? expf(v2 - mx) : 0.f);
        s = wave_sum(s);
        int tcls = (int)w1.y;
        tcls = tcls < 0 ? 0 : (tcls > CC - 1 ? CC - 1 : tcls);
        float vt = ((lane == tcls) ? v1 : 0.f) + ((lane + 64 == tcls) ? v2 : 0.f);
        vt = wave_sum(vt);
        if (lane == 0) acc += (mx + logf(s)) - vt;
    }
    if (lane == 0 && acc != 0.f) atomicAdd(out, acc);
}

// Main kernel: one thread per (a,h,w) cell, blockIdx.y = batch.
// Box records read via wave-uniform (scalarizable) global loads; no division,
// single float-equality match per box.
__global__ __launch_bounds__(256) void region_loss(const float* __restrict__ pred,
                                                   const float4* __restrict__ ws,
                                                   float* __restrict__ out) {
    __shared__ float wsum[4];
    int b = blockIdx.y;
    int tid = threadIdx.x;
    int c = blockIdx.x * 256 + tid;
    float lsum = 0.f;
    if (c < CELLS) {
        int a = c / HWSZ;
        int rem = c - a * HWSZ;
        int hh = rem / WW;
        int wwi = rem - hh * WW;
        size_t base = ((size_t)(b * AA + a) * (CC + 5)) * HWSZ + rem;
        float p0 = pred[base];
        float p1 = pred[base + HWSZ];
        float p2 = pred[base + 2 * HWSZ];
        float p3 = pred[base + 3 * HWSZ];
        float p4 = pred[base + 4 * HWSZ];
        float tx = sig(p0);
        float ty = sig(p1);
        float conf = sig(p4);
        float bx = tx + (float)wwi;
        float by = ty + (float)hh;
        float bw = expf(p2) * d_aw[a];
        float bh = expf(p3) * d_ah[a];
        float px1 = bx - bw * 0.5f, px2 = bx + bw * 0.5f;
        float py1 = by - bh * 0.5f, py2 = by + bh * 0.5f;
        float pa375 = 0.375f * bw * bh;
        float cf = (float)c;

        const float4* lb = ws + LBOX_OFF + (size_t)b * NBOX * 2;
        float hit = -1.f;      // >0 iff some valid box has IoU > 0.6
        int win = -1;
        #pragma unroll 5
        for (int j = 0; j < NBOX; ++j) {
            float4 l0 = lb[j * 2 + 0];
            float4 l1 = lb[j * 2 + 1];
            float iw = fmaxf(fminf(px2, l0.y) - fmaxf(px1, l0.x), 0.f);
            float ih = fmaxf(fminf(py2, l0.w) - fmaxf(py1, l0.z), 0.f);
            float inter = iw * ih;
            // inter/union > 0.6  <=>  inter > 0.375*(parea+area)
            hit = fmaxf(hit, inter - (pa375 + l1.x));
            win = (l1.y == cf) ? j : win;
        }

        float dx, dy, dw, dh, lconf;
        if (win >= 0) {
            const float4* w = ws + WINFO_OFF + ((size_t)b * NBOX + win) * 2;
            float4 w0 = w[0];
            float iou_gt = w[1].x;
            dx = tx - w0.x; dy = ty - w0.y; dw = p2 - w0.z; dh = p3 - w0.w;
            float d = conf - iou_gt;
            lconf = 2.5f * d * d;           // 0.5 * OBJECT_SCALE * (conf - iou_gt)^2
        } else {
            dx = tx - 0.5f; dy = ty - 0.5f; dw = p2; dh = p3;
            float cm = (hit > 0.f) ? 0.f : 1.f;
            lconf = 0.5f * cm * conf * conf;
        }
        lsum = 0.5f * (dx * dx + dy * dy + dw * dw + dh * dh) + lconf;
    }

    #pragma unroll
    for (int off = 32; off > 0; off >>= 1)
        lsum += __shfl_down(lsum, off, 64);
    int wave = tid >> 6;
    if ((tid & 63) == 0) wsum[wave] = lsum;
    __syncthreads();
    if (tid == 0) {
        atomicAdd(out, wsum[0] + wsum[1] + wsum[2] + wsum[3]);
    }
}

extern "C" void kernel_launch(void* const* d_in, const int* in_sizes, int n_in,
                              void* d_out, int out_size, void* d_ws, size_t ws_size,
                              hipStream_t stream) {
    const float* pred = (const float*)d_in[0];
    const float* target = (const float*)d_in[1];
    float* out = (float*)d_out;
    float4* ws = (float4*)d_ws;   // needs 2*BB*NBOX*2*16 = 102400 bytes

    region_prep<<<dim3(BB), dim3(64), 0, stream>>>(pred, target, ws, out, out_size);
    region_ce<<<dim3(BB), dim3(256), 0, stream>>>(pred, ws, out);
    dim3 grid((CELLS + 255) / 256, BB);
    region_loss<<<grid, dim3(256), 0, stream>>>(pred, ws, out);
}